// Round 5
// baseline (685.741 us; speedup 1.0000x reference)
//
#include <hip/hip_runtime.h>
#include <hip/hip_bf16.h>
#include <cstdint>
#include <cstddef>

#define S_LEN 2048
#define NEGV -1e9f
#define QKV_STRIDE 5120

using bf16x8   = __attribute__((ext_vector_type(8))) __bf16;
using bf16x4   = __attribute__((ext_vector_type(4))) __bf16;
using ushort8  = __attribute__((ext_vector_type(8))) unsigned short;
using ushort4v = __attribute__((ext_vector_type(4))) unsigned short;
using f32x4    = __attribute__((ext_vector_type(4))) float;
using uint2v   = __attribute__((ext_vector_type(2))) unsigned int;

template<bool V> struct BoolC { static constexpr bool value = V; };

__device__ __forceinline__ unsigned short f2bf(float f) {
    union { float f; unsigned u; } v; v.f = f;
    unsigned u = v.u;
    return (unsigned short)((u + 0x7fffu + ((u >> 16) & 1u)) >> 16);
}

// pack two positive floats -> {bf16(b),bf16(a)} with round-half-up via v_perm
__device__ __forceinline__ unsigned pk2bf(float a, float b) {
    unsigned ua = __builtin_bit_cast(unsigned, a) + 0x8000u;
    unsigned ub = __builtin_bit_cast(unsigned, b) + 0x8000u;
    return __builtin_amdgcn_perm(ub, ua, 0x07060302u);
}

__device__ __forceinline__ void gld_lds16(const unsigned short* g, unsigned short* l) {
    __builtin_amdgcn_global_load_lds(
        (const __attribute__((address_space(1))) void*)(g),
        (__attribute__((address_space(3))) void*)(l), 16, 0, 0);
}

__device__ __forceinline__ f32x4 mfma32(bf16x8 a, bf16x8 b, f32x4 c) {
    return __builtin_amdgcn_mfma_f32_16x16x32_bf16(a, b, c, 0, 0, 0);
}

__device__ __forceinline__ f32x4 mfma16(ushort4v a, ushort4v b, f32x4 c) {
#if __has_builtin(__builtin_amdgcn_mfma_f32_16x16x16_bf16)
    return __builtin_amdgcn_mfma_f32_16x16x16_bf16(
        __builtin_bit_cast(bf16x4, a), __builtin_bit_cast(bf16x4, b), c, 0, 0, 0);
#else
    return __builtin_amdgcn_mfma_f32_16x16x16bf16_1k(
        __builtin_bit_cast(bf16x4, a), __builtin_bit_cast(bf16x4, b), c, 0, 0, 0);
#endif
}

// -------------------- fused fp32->bf16 convert for all 5 tensors --------------------
__global__ __launch_bounds__(256) void cvt5_kernel(
    const float* __restrict__ X,  const float* __restrict__ Wq,
    const float* __restrict__ Wk, const float* __restrict__ Wv,
    const float* __restrict__ Wo,
    unsigned short* __restrict__ Xb, unsigned short* __restrict__ Wqkvb,
    unsigned short* __restrict__ Wob) {
    int i = blockIdx.x * 256 + threadIdx.x;   // float4 index, total 2621440
    const float* src; unsigned short* dst; int off;
    if      (i < 1048576) { src = X;  dst = Xb;              off = 0;       }
    else if (i < 1572864) { src = Wq; dst = Wqkvb;           off = 1048576; }
    else if (i < 2097152) { src = Wk; dst = Wqkvb + 2097152; off = 1572864; }
    else if (i < 2359296) { src = Wv; dst = Wqkvb + 4194304; off = 2097152; }
    else                  { src = Wo; dst = Wob;             off = 2359296; }
    int j = i - off;
    float4 v = ((const float4*)src)[j];
    ushort4v t;
    t.x = f2bf(v.x); t.y = f2bf(v.y); t.z = f2bf(v.z); t.w = f2bf(v.w);
    ((ushort4v*)dst)[j] = t;
}

// -------------------- lambda + stats zero + colt table [b][h][k] --------------------
__global__ __launch_bounds__(256) void lamcolt_kernel(
    const float* __restrict__ lq1, const float* __restrict__ lk1,
    const float* __restrict__ lq2, const float* __restrict__ lk2,
    const int* __restrict__ tok, const float* __restrict__ amask,
    float* __restrict__ lam_ws, float* __restrict__ sum_ws,
    float* __restrict__ sumsq_ws, float* __restrict__ colt_g) {
    const int gid = blockIdx.x * 256 + threadIdx.x;
    if (blockIdx.x == 0) {
        int t = threadIdx.x;
        if (t >= 64 && t < 96)  sum_ws[t - 64] = 0.f;
        if (t >= 96 && t < 128) sumsq_ws[t - 96] = 0.f;
        if (t < 64) {
            float a = lq1[t] * lk1[t];
            float b = lq2[t] * lk2[t];
            for (int off = 32; off > 0; off >>= 1) {
                a += __shfl_xor(a, off);
                b += __shfl_xor(b, off);
            }
            if (t == 0) lam_ws[0] = __expf(a) - __expf(b) + 0.8f;
        }
    }
    const int b = gid >> 13, h = (gid >> 9) & 15, k = (gid & 511) * 4;
    const float slope2 = exp2f(-0.5f * (float)(h + 1)) * 1.44269504f;
    int4   t4 = *(const int4*)(tok + b * S_LEN + k);
    float4 a4 = *(const float4*)(amask + b * S_LEN + k);
    float4 o;
    o.x = slope2 * (float)t4.x + (1.f - a4.x) * NEGV;
    o.y = slope2 * (float)t4.y + (1.f - a4.y) * NEGV;
    o.z = slope2 * (float)t4.z + (1.f - a4.z) * NEGV;
    o.w = slope2 * (float)t4.w + (1.f - a4.w) * NEGV;
    *(float4*)(colt_g + (size_t)((b * 16 + h) * S_LEN + k)) = o;
}

// -------------------- V transpose: VT[bh][d][k] --------------------
__global__ __launch_bounds__(256) void vt_kernel(const unsigned short* __restrict__ QKV,
                                                 unsigned short* __restrict__ VT) {
    const int k0 = blockIdx.x * 64, bh = blockIdx.y;
    const int b = bh >> 4, h = bh & 15;
    __shared__ unsigned short T[64 * 72];
    const int tid = threadIdx.x;
    const int r = tid >> 2, ds = (tid & 3) * 16;
    const unsigned short* vp = QKV + (size_t)(b * S_LEN + k0 + r) * QKV_STRIDE + 4096 + h * 64 + ds;
    ushort8 a = *(const ushort8*)vp;
    ushort8 c = *(const ushort8*)(vp + 8);
#pragma unroll
    for (int j = 0; j < 8; j++) {
        T[(ds + j) * 72 + r]     = a[j];
        T[(ds + 8 + j) * 72 + r] = c[j];
    }
    __syncthreads();
    const int d = tid >> 2, ks = (tid & 3) * 16;
    unsigned short* op = VT + ((size_t)bh * 64 + d) * 2048 + k0 + ks;
    *(ushort8*)(op)     = *(const ushort8*)(T + d * 72 + ks);
    *(ushort8*)(op + 8) = *(const ushort8*)(T + d * 72 + ks + 8);
}

// -------------------- GEMM: C[M,N] = A[M,K] @ B[N,K]^T (bf16 in) --------------------
template<bool C_BF16>
__global__ __launch_bounds__(256) void gemm_bt(const unsigned short* __restrict__ A,
                                               const unsigned short* __restrict__ B,
                                               void* __restrict__ C_,
                                               int M, int N, int K) {
    const int m0 = blockIdx.y * 128;
    const int n0 = blockIdx.x * 128;
    __shared__ __align__(16) unsigned short As[128 * 64];
    __shared__ __align__(16) unsigned short Bs[128 * 64];
    const int tid  = threadIdx.x;
    const int lane = tid & 63;
    const int w    = tid >> 6;
    const int wm   = (w >> 1) * 64, wn = (w & 1) * 64;
    const int col  = lane & 15, quad = lane >> 4;

    f32x4 acc[4][4] = {};

    const int srow = lane >> 3;
    const int gcol = ((lane & 7) ^ srow) * 8;

    for (int k0 = 0; k0 < K; k0 += 64) {
        __syncthreads();
        const unsigned short* Ag = A + (size_t)m0 * K + k0 + gcol;
        const unsigned short* Bg = B + (size_t)n0 * K + k0 + gcol;
#pragma unroll
        for (int i = 0; i < 4; i++) {
            const int blk = w * 4 + i;
            gld_lds16(Ag + (size_t)(blk * 8 + srow) * K, As + blk * 512);
            gld_lds16(Bg + (size_t)(blk * 8 + srow) * K, Bs + blk * 512);
        }
        __syncthreads();

#pragma unroll
        for (int kk = 0; kk < 2; kk++) {
            const int swz = ((kk * 4 + quad) ^ (col & 7)) * 8;
            bf16x8 af[4], bb[4];
#pragma unroll
            for (int mi = 0; mi < 4; mi++)
                af[mi] = *(const bf16x8*)(As + (wm + mi * 16 + col) * 64 + swz);
#pragma unroll
            for (int ni = 0; ni < 4; ni++)
                bb[ni] = *(const bf16x8*)(Bs + (wn + ni * 16 + col) * 64 + swz);
#pragma unroll
            for (int mi = 0; mi < 4; mi++)
#pragma unroll
                for (int ni = 0; ni < 4; ni++)
                    acc[mi][ni] = mfma32(af[mi], bb[ni], acc[mi][ni]);
        }
    }

#pragma unroll
    for (int mi = 0; mi < 4; mi++)
#pragma unroll
        for (int ni = 0; ni < 4; ni++)
#pragma unroll
            for (int r = 0; r < 4; r++) {
                const int row = m0 + wm + mi * 16 + quad * 4 + r;
                const int cc  = n0 + wn + ni * 16 + col;
                if constexpr (C_BF16)
                    ((unsigned short*)C_)[(size_t)row * N + cc] = f2bf(acc[mi][ni][r]);
                else
                    ((float*)C_)[(size_t)row * N + cc] = acc[mi][ni][r];
            }
}

// -------------------- differential flash attention (no LDS, no syncthreads) --------------------
// S^T = K.Q^T, fragments loaded straight from global (K rows, pre-transposed VT rows,
// colt table) — L2-hot across the 32 q-blocks per bh; the block's 4 waves read identical
// addresses -> L1 broadcast. exp'd P^T feeds mfma16 B-operand from registers. Bare
// s_barrier (no memory drain) keeps waves aligned for L1 locality.
__global__ __launch_bounds__(256, 4) void attn_kernel(
    const unsigned short* __restrict__ QKV, const unsigned short* __restrict__ VT,
    const int* __restrict__ tok, const float* __restrict__ colt_g,
    const float* __restrict__ lam_ws, unsigned short* __restrict__ attnb,
    float* __restrict__ sum_ws, float* __restrict__ sumsq_ws)
{
    const int qt = (int)gridDim.x - 1 - (int)blockIdx.x;   // heavy first
    const int bh = blockIdx.y;
    const int b = bh >> 4, h = bh & 15;
    const int q0 = qt * 64;
    const int tid = threadIdx.x, lane = tid & 63, w = tid >> 6;
    const int col = lane & 15, quad = lane >> 4;

    const float LOG2E = 1.44269504f;
    const float slope2 = exp2f(-0.5f * (float)(h + 1)) * LOG2E;
    const float scale2 = 0.125f * LOG2E;

    // Q fragments as B-operand (n = lane&15 -> q, k = quad*8+j -> d)
    const unsigned short* qp = QKV + (size_t)(b * S_LEN + q0 + w * 16 + col) * QKV_STRIDE + h * 128;
    bf16x8 q1f0 = *(const bf16x8*)(qp + quad * 8);
    bf16x8 q1f1 = *(const bf16x8*)(qp + 32 + quad * 8);
    bf16x8 q2f0 = *(const bf16x8*)(qp + 64 + quad * 8);
    bf16x8 q2f1 = *(const bf16x8*)(qp + 96 + quad * 8);

    const int qidx = q0 + w * 16 + col;
    const float rowt = -slope2 * (float)tok[b * S_LEN + qidx];
    const float* cg = colt_g + (size_t)bh * S_LEN;

    // K fragment base: A[m = key = mt*16+col][k = d], d-chunks at quad*8 (+0/32/64/96)
    const unsigned short* kfb = QKV + ((size_t)(b * S_LEN + col)) * QKV_STRIDE + 2048 + h * 128 + quad * 8;
    // VT fragment base: A[m = d = dt*16+col][k = key = quad*4+j]
    const unsigned short* vtb = VT + ((size_t)bh * 64 + col) * 2048 + quad * 4;

    float l1 = 0.f, l2 = 0.f;
    f32x4 O1[4] = {}, O2[4] = {};

    auto tile = [&](int kt, auto causal_tag) {
        constexpr bool CAUSAL = decltype(causal_tag)::value;
        const int k0 = kt * 64;
        __builtin_amdgcn_s_barrier();   // alignment only: no fence, no vmcnt drain
#pragma unroll
        for (int mt = 0; mt < 4; mt++) {
            const unsigned short* kr = kfb + (size_t)(k0 + mt * 16) * QKV_STRIDE;
            bf16x8 k1a = *(const bf16x8*)(kr);
            bf16x8 k1b = *(const bf16x8*)(kr + 32);
            bf16x8 k2a = *(const bf16x8*)(kr + 64);
            bf16x8 k2b = *(const bf16x8*)(kr + 96);
            float4 ct  = *(const float4*)(cg + k0 + mt * 16 + quad * 4);
            ushort4v vf0 = *(const ushort4v*)(vtb + 0 * 32768 + k0 + mt * 16);
            ushort4v vf1 = *(const ushort4v*)(vtb + 1 * 32768 + k0 + mt * 16);
            ushort4v vf2 = *(const ushort4v*)(vtb + 2 * 32768 + k0 + mt * 16);
            ushort4v vf3 = *(const ushort4v*)(vtb + 3 * 32768 + k0 + mt * 16);

            f32x4 s1 = {}, s2 = {};
            s1 = mfma32(k1a, q1f0, s1);
            s1 = mfma32(k1b, q1f1, s1);
            s2 = mfma32(k2a, q2f0, s2);
            s2 = mfma32(k2b, q2f1, s2);

            float p[4], r2v[4];
#pragma unroll
            for (int r = 0; r < 4; r++) {
                float base = rowt + (&ct.x)[r];
                if constexpr (CAUSAL) {
                    int key = k0 + mt * 16 + quad * 4 + r;
                    base = (key > qidx) ? -1e9f : base;
                }
                p[r]   = exp2f(s1[r] * scale2 + base);
                r2v[r] = exp2f(s2[r] * scale2 + base);
            }
            l1 += (p[0] + p[1]) + (p[2] + p[3]);
            l2 += (r2v[0] + r2v[1]) + (r2v[2] + r2v[3]);
            uint2v u1; u1.x = pk2bf(p[0], p[1]);     u1.y = pk2bf(p[2], p[3]);
            uint2v u2; u2.x = pk2bf(r2v[0], r2v[1]); u2.y = pk2bf(r2v[2], r2v[3]);
            ushort4v pf1 = __builtin_bit_cast(ushort4v, u1);
            ushort4v pf2 = __builtin_bit_cast(ushort4v, u2);

            O1[0] = mfma16(vf0, pf1, O1[0]);  O2[0] = mfma16(vf0, pf2, O2[0]);
            O1[1] = mfma16(vf1, pf1, O1[1]);  O2[1] = mfma16(vf1, pf2, O2[1]);
            O1[2] = mfma16(vf2, pf1, O1[2]);  O2[2] = mfma16(vf2, pf2, O2[2]);
            O1[3] = mfma16(vf3, pf1, O1[3]);  O2[3] = mfma16(vf3, pf2, O2[3]);
        }
    };

    for (int kt = 0; kt < qt; kt++) tile(kt, BoolC<false>{});
    tile(qt, BoolC<true>{});

    // cross-quad l reduction (once)
    l1 += __shfl_xor(l1, 16); l1 += __shfl_xor(l1, 32);
    l2 += __shfl_xor(l2, 16); l2 += __shfl_xor(l2, 32);

    const float lam = lam_ws[0];
    const float il1 = 1.0f / l1, il2 = lam / l2;
    float s = 0.f, ss = 0.f;
    unsigned short* op = attnb + (size_t)(b * S_LEN + qidx) * 1024 + h * 64;
#pragma unroll
    for (int dt = 0; dt < 4; dt++) {
        f32x4 o = O1[dt] * il1 - O2[dt] * il2;
        ushort4v t;
        t.x = f2bf(o[0]); t.y = f2bf(o[1]); t.z = f2bf(o[2]); t.w = f2bf(o[3]);
        *(ushort4v*)(op + dt * 16 + quad * 4) = t;
        s  += (o[0] + o[1]) + (o[2] + o[3]);
        ss += (o[0]*o[0] + o[1]*o[1]) + (o[2]*o[2] + o[3]*o[3]);
    }
    for (int off = 1; off < 64; off <<= 1) { s += __shfl_xor(s, off); ss += __shfl_xor(ss, off); }
    if (lane == 0) {
        atomicAdd(&sum_ws[bh], s);
        atomicAdd(&sumsq_ws[bh], ss);
    }
}

// -------------------- normalize + gamma/beta + *0.2 (bf16 in/out) --------------------
__global__ __launch_bounds__(256) void norm_kernel(const unsigned short* __restrict__ attnb,
    const float* __restrict__ sum_ws, const float* __restrict__ sumsq_ws,
    const float* __restrict__ gamma, const float* __restrict__ beta,
    unsigned short* __restrict__ outb) {
    size_t i = ((size_t)blockIdx.x * 256 + threadIdx.x) * 8;
    ushort8 x8 = *(const ushort8*)(attnb + i);
    int c   = (int)(i & 1023);
    int row = (int)(i >> 10);
    int bi  = (row >> 11) * 16 + (c >> 6);
    const float inv_n = 1.0f / (float)(S_LEN * 64);
    float mu = sum_ws[bi] * inv_n;
    float var = fmaxf(sumsq_ws[bi] * inv_n - mu * mu, 0.0f);
    float iv = rsqrtf(var + 1e-5f);
    ushort8 t;
#pragma unroll
    for (int j = 0; j < 8; j++) {
        union { unsigned u; float f; } cv; cv.u = (unsigned)x8[j] << 16;
        t[j] = f2bf(((cv.f - mu) * iv * gamma[c + j] + beta[c + j]) * 0.2f);
    }
    *(ushort8*)(outb + i) = t;
}

// -------------------- launch --------------------
extern "C" void kernel_launch(void* const* d_in, const int* in_sizes, int n_in,
                              void* d_out, int out_size, void* d_ws, size_t ws_size,
                              hipStream_t stream) {
    const float* inputs = (const float*)d_in[0];
    const float* amask  = (const float*)d_in[1];
    const int*   tok    = (const int*)d_in[2];
    const float* Wq     = (const float*)d_in[3];
    const float* Wk     = (const float*)d_in[4];
    const float* Wv     = (const float*)d_in[5];
    const float* Wo     = (const float*)d_in[6];
    const float* lq1    = (const float*)d_in[7];
    const float* lq2    = (const float*)d_in[8];
    const float* lk1    = (const float*)d_in[9];
    const float* lk2    = (const float*)d_in[10];
    const float* gamma  = (const float*)d_in[11];
    const float* beta   = (const float*)d_in[12];
    float* out = (float*)d_out;

    char* ws = (char*)d_ws;
    float* lam_ws   = (float*)ws;
    float* sum_ws   = (float*)(ws + 256);
    float* sumsq_ws = (float*)(ws + 512);
    float* colt_g   = (float*)(ws + 1024);          // 65536 floats = 256 KB
    unsigned short* Wob   = (unsigned short*)(ws + 1024 + 262144);
    unsigned short* QKVb  = Wob + 1048576;          // 4096 x 5120
    unsigned short* Xb    = QKVb + 20971520;        // 4096 x 1024
    unsigned short* Wqkvb = Xb + 4194304;           // 5120 x 1024
    unsigned short* VTb   = Wqkvb + 5242880;        // 32 x 64 x 2048
    unsigned short* attnb = Xb;                     // alias (X dead after QKV GEMM)
    unsigned short* normb = QKVb;                   // alias (QKV dead after attention)

    cvt5_kernel<<<10240, 256, 0, stream>>>(inputs, Wq, Wk, Wv, Wo, Xb, Wqkvb, Wob);
    lamcolt_kernel<<<64, 256, 0, stream>>>(lq1, lk1, lq2, lk2, tok, amask,
                                           lam_ws, sum_ws, sumsq_ws, colt_g);
    gemm_bt<true><<<dim3(40, 32), 256, 0, stream>>>(Xb, Wqkvb, QKVb, 4096, 5120, 1024);
    vt_kernel<<<dim3(32, 32), 256, 0, stream>>>(QKVb, VTb);
    attn_kernel<<<dim3(32, 32), 256, 0, stream>>>(QKVb, VTb, tok, colt_g, lam_ws,
                                                  attnb, sum_ws, sumsq_ws);
    norm_kernel<<<2048, 256, 0, stream>>>(attnb, sum_ws, sumsq_ws, gamma, beta, normb);
    gemm_bt<false><<<dim3(8, 32), 256, 0, stream>>>(normb, Wob, out, 4096, 1024, 1024);
}

// Round 6
// 292.554 us; speedup vs baseline: 2.3440x; 2.3440x over previous
//
#include <hip/hip_runtime.h>
#include <hip/hip_bf16.h>
#include <cstdint>
#include <cstddef>

#define S_LEN 2048
#define NEGV -1e9f
#define QKV_STRIDE 5120

using bf16x8   = __attribute__((ext_vector_type(8))) __bf16;
using bf16x4   = __attribute__((ext_vector_type(4))) __bf16;
using ushort8  = __attribute__((ext_vector_type(8))) unsigned short;
using ushort4v = __attribute__((ext_vector_type(4))) unsigned short;
using f32x4    = __attribute__((ext_vector_type(4))) float;
using uint2v   = __attribute__((ext_vector_type(2))) unsigned int;

template<bool V> struct BoolC { static constexpr bool value = V; };

__device__ __forceinline__ unsigned short f2bf(float f) {
    union { float f; unsigned u; } v; v.f = f;
    unsigned u = v.u;
    return (unsigned short)((u + 0x7fffu + ((u >> 16) & 1u)) >> 16);
}

// pack two positive floats -> {bf16(b),bf16(a)} with round-half-up via v_perm
__device__ __forceinline__ unsigned pk2bf(float a, float b) {
    unsigned ua = __builtin_bit_cast(unsigned, a) + 0x8000u;
    unsigned ub = __builtin_bit_cast(unsigned, b) + 0x8000u;
    return __builtin_amdgcn_perm(ub, ua, 0x07060302u);
}

__device__ __forceinline__ void gld_lds16(const unsigned short* g, unsigned short* l) {
    __builtin_amdgcn_global_load_lds(
        (const __attribute__((address_space(1))) void*)(g),
        (__attribute__((address_space(3))) void*)(l), 16, 0, 0);
}

__device__ __forceinline__ f32x4 mfma32(bf16x8 a, bf16x8 b, f32x4 c) {
    return __builtin_amdgcn_mfma_f32_16x16x32_bf16(a, b, c, 0, 0, 0);
}

__device__ __forceinline__ f32x4 mfma16(ushort4v a, ushort4v b, f32x4 c) {
#if __has_builtin(__builtin_amdgcn_mfma_f32_16x16x16_bf16)
    return __builtin_amdgcn_mfma_f32_16x16x16_bf16(
        __builtin_bit_cast(bf16x4, a), __builtin_bit_cast(bf16x4, b), c, 0, 0, 0);
#else
    return __builtin_amdgcn_mfma_f32_16x16x16bf16_1k(
        __builtin_bit_cast(bf16x4, a), __builtin_bit_cast(bf16x4, b), c, 0, 0, 0);
#endif
}

// -------------------- fused fp32->bf16 convert for all 5 tensors --------------------
__global__ __launch_bounds__(256) void cvt5_kernel(
    const float* __restrict__ X,  const float* __restrict__ Wq,
    const float* __restrict__ Wk, const float* __restrict__ Wv,
    const float* __restrict__ Wo,
    unsigned short* __restrict__ Xb, unsigned short* __restrict__ Wqkvb,
    unsigned short* __restrict__ Wob) {
    int i = blockIdx.x * 256 + threadIdx.x;   // float4 index, total 2621440
    const float* src; unsigned short* dst; int off;
    if      (i < 1048576) { src = X;  dst = Xb;              off = 0;       }
    else if (i < 1572864) { src = Wq; dst = Wqkvb;           off = 1048576; }
    else if (i < 2097152) { src = Wk; dst = Wqkvb + 2097152; off = 1572864; }
    else if (i < 2359296) { src = Wv; dst = Wqkvb + 4194304; off = 2097152; }
    else                  { src = Wo; dst = Wob;             off = 2359296; }
    int j = i - off;
    float4 v = ((const float4*)src)[j];
    ushort4v t;
    t.x = f2bf(v.x); t.y = f2bf(v.y); t.z = f2bf(v.z); t.w = f2bf(v.w);
    ((ushort4v*)dst)[j] = t;
}

// -------------------- lambda + stats zero + colt table [b][h][k] --------------------
__global__ __launch_bounds__(256) void lamcolt_kernel(
    const float* __restrict__ lq1, const float* __restrict__ lk1,
    const float* __restrict__ lq2, const float* __restrict__ lk2,
    const int* __restrict__ tok, const float* __restrict__ amask,
    float* __restrict__ lam_ws, float* __restrict__ sum_ws,
    float* __restrict__ sumsq_ws, float* __restrict__ colt_g) {
    const int gid = blockIdx.x * 256 + threadIdx.x;
    if (blockIdx.x == 0) {
        int t = threadIdx.x;
        if (t >= 64 && t < 96)  sum_ws[t - 64] = 0.f;
        if (t >= 96 && t < 128) sumsq_ws[t - 96] = 0.f;
        if (t < 64) {
            float a = lq1[t] * lk1[t];
            float b = lq2[t] * lk2[t];
            for (int off = 32; off > 0; off >>= 1) {
                a += __shfl_xor(a, off);
                b += __shfl_xor(b, off);
            }
            if (t == 0) lam_ws[0] = __expf(a) - __expf(b) + 0.8f;
        }
    }
    const int b = gid >> 13, h = (gid >> 9) & 15, k = (gid & 511) * 4;
    const float slope2 = exp2f(-0.5f * (float)(h + 1)) * 1.44269504f;
    int4   t4 = *(const int4*)(tok + b * S_LEN + k);
    float4 a4 = *(const float4*)(amask + b * S_LEN + k);
    float4 o;
    o.x = slope2 * (float)t4.x + (1.f - a4.x) * NEGV;
    o.y = slope2 * (float)t4.y + (1.f - a4.y) * NEGV;
    o.z = slope2 * (float)t4.z + (1.f - a4.z) * NEGV;
    o.w = slope2 * (float)t4.w + (1.f - a4.w) * NEGV;
    *(float4*)(colt_g + (size_t)((b * 16 + h) * S_LEN + k)) = o;
}

// -------------------- V transpose: VT[bh][d][k] --------------------
__global__ __launch_bounds__(256) void vt_kernel(const unsigned short* __restrict__ QKV,
                                                 unsigned short* __restrict__ VT) {
    const int k0 = blockIdx.x * 64, bh = blockIdx.y;
    const int b = bh >> 4, h = bh & 15;
    __shared__ unsigned short T[64 * 72];
    const int tid = threadIdx.x;
    const int r = tid >> 2, ds = (tid & 3) * 16;
    const unsigned short* vp = QKV + (size_t)(b * S_LEN + k0 + r) * QKV_STRIDE + 4096 + h * 64 + ds;
    ushort8 a = *(const ushort8*)vp;
    ushort8 c = *(const ushort8*)(vp + 8);
#pragma unroll
    for (int j = 0; j < 8; j++) {
        T[(ds + j) * 72 + r]     = a[j];
        T[(ds + 8 + j) * 72 + r] = c[j];
    }
    __syncthreads();
    const int d = tid >> 2, ks = (tid & 3) * 16;
    unsigned short* op = VT + ((size_t)bh * 64 + d) * 2048 + k0 + ks;
    *(ushort8*)(op)     = *(const ushort8*)(T + d * 72 + ks);
    *(ushort8*)(op + 8) = *(const ushort8*)(T + d * 72 + ks + 8);
}

// -------------------- GEMM: C[M,N] = A[M,K] @ B[N,K]^T (bf16 in) --------------------
template<bool C_BF16>
__global__ __launch_bounds__(256) void gemm_bt(const unsigned short* __restrict__ A,
                                               const unsigned short* __restrict__ B,
                                               void* __restrict__ C_,
                                               int M, int N, int K) {
    const int m0 = blockIdx.y * 128;
    const int n0 = blockIdx.x * 128;
    __shared__ __align__(16) unsigned short As[128 * 64];
    __shared__ __align__(16) unsigned short Bs[128 * 64];
    const int tid  = threadIdx.x;
    const int lane = tid & 63;
    const int w    = tid >> 6;
    const int wm   = (w >> 1) * 64, wn = (w & 1) * 64;
    const int col  = lane & 15, quad = lane >> 4;

    f32x4 acc[4][4] = {};

    const int srow = lane >> 3;
    const int gcol = ((lane & 7) ^ srow) * 8;

    for (int k0 = 0; k0 < K; k0 += 64) {
        __syncthreads();
        const unsigned short* Ag = A + (size_t)m0 * K + k0 + gcol;
        const unsigned short* Bg = B + (size_t)n0 * K + k0 + gcol;
#pragma unroll
        for (int i = 0; i < 4; i++) {
            const int blk = w * 4 + i;
            gld_lds16(Ag + (size_t)(blk * 8 + srow) * K, As + blk * 512);
            gld_lds16(Bg + (size_t)(blk * 8 + srow) * K, Bs + blk * 512);
        }
        __syncthreads();

#pragma unroll
        for (int kk = 0; kk < 2; kk++) {
            const int swz = ((kk * 4 + quad) ^ (col & 7)) * 8;
            bf16x8 af[4], bb[4];
#pragma unroll
            for (int mi = 0; mi < 4; mi++)
                af[mi] = *(const bf16x8*)(As + (wm + mi * 16 + col) * 64 + swz);
#pragma unroll
            for (int ni = 0; ni < 4; ni++)
                bb[ni] = *(const bf16x8*)(Bs + (wn + ni * 16 + col) * 64 + swz);
#pragma unroll
            for (int mi = 0; mi < 4; mi++)
#pragma unroll
                for (int ni = 0; ni < 4; ni++)
                    acc[mi][ni] = mfma32(af[mi], bb[ni], acc[mi][ni]);
        }
    }

#pragma unroll
    for (int mi = 0; mi < 4; mi++)
#pragma unroll
        for (int ni = 0; ni < 4; ni++)
#pragma unroll
            for (int r = 0; r < 4; r++) {
                const int row = m0 + wm + mi * 16 + quad * 4 + r;
                const int cc  = n0 + wn + ni * 16 + col;
                if constexpr (C_BF16)
                    ((unsigned short*)C_)[(size_t)row * N + cc] = f2bf(acc[mi][ni][r]);
                else
                    ((float*)C_)[(size_t)row * N + cc] = acc[mi][ni][r];
            }
}

// -------------------- differential flash attention (paired q-tiles, LDS-staged) --------------------
// Block processes q-tiles {qa, 31-qa} sequentially -> exactly 33 tile-computes per
// block (perfect balance). S^T = K.Q^T; exp'd P^T feeds mfma16 B-operand from regs.
// K and pre-transposed VT staged via swizzled global_load_lds, double-buffered;
// prefetch issued after the barrier so it stays in flight across a full tile.
__global__ __launch_bounds__(256, 3) void attn_kernel(
    const unsigned short* __restrict__ QKV, const unsigned short* __restrict__ VT,
    const int* __restrict__ tok, const float* __restrict__ colt_g,
    const float* __restrict__ lam_ws, unsigned short* __restrict__ attnb,
    float* __restrict__ sum_ws, float* __restrict__ sumsq_ws)
{
    const int bh = blockIdx.y;
    const int b = bh >> 4, h = bh & 15;
    const int tid = threadIdx.x, lane = tid & 63, w = tid >> 6;
    const int col = lane & 15, quad = lane >> 4;

    __shared__ __align__(16) unsigned short Kbuf[2][8192];  // [buf][K1:4096 | K2:4096]
    __shared__ __align__(16) unsigned short VTs[2][4096];   // [buf][64 d x 64 k], swizzled

    const float LOG2E = 1.44269504f;
    const float slope2 = exp2f(-0.5f * (float)(h + 1)) * LOG2E;
    const float scale2 = 0.125f * LOG2E;
    const float* cg = colt_g + (size_t)bh * S_LEN;

    const int srow  = lane >> 3;
    const int kgcol = ((lane & 7) ^ srow) * 8;     // swizzled 16B group
    const unsigned short* kbase  = QKV + 2048 + h * 128 + kgcol;
    const unsigned short* vtbase = VT + (size_t)bh * 131072 + kgcol;

    const float lam = lam_ws[0];
    float s = 0.f, ss = 0.f;

    auto run = [&](int qt) {
        const int q0 = qt * 64;
        const int qidx = q0 + w * 16 + col;
        const unsigned short* qp = QKV + (size_t)(b * S_LEN + qidx) * QKV_STRIDE + h * 128;
        bf16x8 q1f0 = *(const bf16x8*)(qp + quad * 8);
        bf16x8 q1f1 = *(const bf16x8*)(qp + 32 + quad * 8);
        bf16x8 q2f0 = *(const bf16x8*)(qp + 64 + quad * 8);
        bf16x8 q2f1 = *(const bf16x8*)(qp + 96 + quad * 8);
        const float rowt = -slope2 * (float)tok[b * S_LEN + qidx];

        float l1 = 0.f, l2 = 0.f;
        f32x4 O1[4] = {}, O2[4] = {};

        __syncthreads();   // prior run's LDS reads complete before restaging buf0
        {
            const unsigned short* kg = kbase + (size_t)(b * S_LEN) * QKV_STRIDE;
#pragma unroll
            for (int i = 0; i < 2; i++) {
                int blk = w * 2 + i;
                gld_lds16(kg + (size_t)(blk * 8 + srow) * QKV_STRIDE,      &Kbuf[0][blk * 512]);
                gld_lds16(kg + (size_t)(blk * 8 + srow) * QKV_STRIDE + 64, &Kbuf[0][4096 + blk * 512]);
                gld_lds16(vtbase + (size_t)(blk * 8 + srow) * 2048,        &VTs[0][blk * 512]);
            }
        }

        auto tile = [&](int kt, auto causal_tag) {
            constexpr bool CAUSAL = decltype(causal_tag)::value;
            const int cur = kt & 1;
            const int k0 = kt * 64;
            __syncthreads();   // drains glds of tile kt (issued one barrier ago)

            if (kt < qt) {     // prefetch kt+1 AFTER barrier: in flight across compute
                const int k1 = k0 + 64;
                const unsigned short* kg = kbase + (size_t)(b * S_LEN + k1) * QKV_STRIDE;
#pragma unroll
                for (int i = 0; i < 2; i++) {
                    int blk = w * 2 + i;
                    gld_lds16(kg + (size_t)(blk * 8 + srow) * QKV_STRIDE,      &Kbuf[cur ^ 1][blk * 512]);
                    gld_lds16(kg + (size_t)(blk * 8 + srow) * QKV_STRIDE + 64, &Kbuf[cur ^ 1][4096 + blk * 512]);
                    gld_lds16(vtbase + (size_t)(blk * 8 + srow) * 2048 + k1,   &VTs[cur ^ 1][blk * 512]);
                }
            }

            const unsigned short* K1s = &Kbuf[cur][0];
            const unsigned short* K2s = &Kbuf[cur][4096];
            const int sw0 = (quad ^ (col & 7)) * 8;
            const int sw1 = ((4 + quad) ^ (col & 7)) * 8;
#pragma unroll
            for (int mt = 0; mt < 4; mt++) {
                const unsigned short* kr1 = K1s + (mt * 16 + col) * 64;
                const unsigned short* kr2 = K2s + (mt * 16 + col) * 64;
                f32x4 s1 = {}, s2 = {};
                s1 = mfma32(*(const bf16x8*)(kr1 + sw0), q1f0, s1);
                s1 = mfma32(*(const bf16x8*)(kr1 + sw1), q1f1, s1);
                s2 = mfma32(*(const bf16x8*)(kr2 + sw0), q2f0, s2);
                s2 = mfma32(*(const bf16x8*)(kr2 + sw1), q2f1, s2);
                float4 ct = *(const float4*)(cg + k0 + mt * 16 + quad * 4);
                float p[4], r2v[4];
#pragma unroll
                for (int r = 0; r < 4; r++) {
                    float base = rowt + (&ct.x)[r];
                    if constexpr (CAUSAL) {
                        int key = k0 + mt * 16 + quad * 4 + r;
                        base = (key > qidx) ? -1e9f : base;
                    }
                    p[r]   = exp2f(s1[r] * scale2 + base);
                    r2v[r] = exp2f(s2[r] * scale2 + base);
                }
                l1 += (p[0] + p[1]) + (p[2] + p[3]);
                l2 += (r2v[0] + r2v[1]) + (r2v[2] + r2v[3]);
                uint2v u1; u1.x = pk2bf(p[0], p[1]);     u1.y = pk2bf(p[2], p[3]);
                uint2v u2; u2.x = pk2bf(r2v[0], r2v[1]); u2.y = pk2bf(r2v[2], r2v[3]);
                ushort4v pf1 = __builtin_bit_cast(ushort4v, u1);
                ushort4v pf2 = __builtin_bit_cast(ushort4v, u2);
                // VT frag: A[m=d=dt*16+col][k=key=quad*4+j], swizzled slot
                const int voff = ((mt * 2 + (quad >> 1)) ^ (col & 7)) * 8 + (quad & 1) * 4;
#pragma unroll
                for (int dt = 0; dt < 4; dt++) {
                    ushort4v vf = *(const ushort4v*)(VTs[cur] + (dt * 16 + col) * 64 + voff);
                    O1[dt] = mfma16(vf, pf1, O1[dt]);
                    O2[dt] = mfma16(vf, pf2, O2[dt]);
                }
            }
        };

        for (int kt = 0; kt < qt; kt++) tile(kt, BoolC<false>{});
        tile(qt, BoolC<true>{});

        l1 += __shfl_xor(l1, 16); l1 += __shfl_xor(l1, 32);
        l2 += __shfl_xor(l2, 16); l2 += __shfl_xor(l2, 32);
        const float il1 = 1.0f / l1, il2 = lam / l2;
        unsigned short* op = attnb + (size_t)(b * S_LEN + qidx) * 1024 + h * 64;
#pragma unroll
        for (int dt = 0; dt < 4; dt++) {
            f32x4 o = O1[dt] * il1 - O2[dt] * il2;
            ushort4v t;
            t.x = f2bf(o[0]); t.y = f2bf(o[1]); t.z = f2bf(o[2]); t.w = f2bf(o[3]);
            *(ushort4v*)(op + dt * 16 + quad * 4) = t;
            s  += (o[0] + o[1]) + (o[2] + o[3]);
            ss += (o[0]*o[0] + o[1]*o[1]) + (o[2]*o[2] + o[3]*o[3]);
        }
    };

    run((int)blockIdx.x);           // light tile (qa)
    run(31 - (int)blockIdx.x);      // heavy tile (31-qa): total 33 tiles per block

    for (int off = 1; off < 64; off <<= 1) { s += __shfl_xor(s, off); ss += __shfl_xor(ss, off); }
    if (lane == 0) {
        atomicAdd(&sum_ws[bh], s);
        atomicAdd(&sumsq_ws[bh], ss);
    }
}

// -------------------- normalize + gamma/beta + *0.2 (bf16 in/out) --------------------
__global__ __launch_bounds__(256) void norm_kernel(const unsigned short* __restrict__ attnb,
    const float* __restrict__ sum_ws, const float* __restrict__ sumsq_ws,
    const float* __restrict__ gamma, const float* __restrict__ beta,
    unsigned short* __restrict__ outb) {
    size_t i = ((size_t)blockIdx.x * 256 + threadIdx.x) * 8;
    ushort8 x8 = *(const ushort8*)(attnb + i);
    int c   = (int)(i & 1023);
    int row = (int)(i >> 10);
    int bi  = (row >> 11) * 16 + (c >> 6);
    const float inv_n = 1.0f / (float)(S_LEN * 64);
    float mu = sum_ws[bi] * inv_n;
    float var = fmaxf(sumsq_ws[bi] * inv_n - mu * mu, 0.0f);
    float iv = rsqrtf(var + 1e-5f);
    ushort8 t;
#pragma unroll
    for (int j = 0; j < 8; j++) {
        union { unsigned u; float f; } cv; cv.u = (unsigned)x8[j] << 16;
        t[j] = f2bf(((cv.f - mu) * iv * gamma[c + j] + beta[c + j]) * 0.2f);
    }
    *(ushort8*)(outb + i) = t;
}

// -------------------- launch --------------------
extern "C" void kernel_launch(void* const* d_in, const int* in_sizes, int n_in,
                              void* d_out, int out_size, void* d_ws, size_t ws_size,
                              hipStream_t stream) {
    const float* inputs = (const float*)d_in[0];
    const float* amask  = (const float*)d_in[1];
    const int*   tok    = (const int*)d_in[2];
    const float* Wq     = (const float*)d_in[3];
    const float* Wk     = (const float*)d_in[4];
    const float* Wv     = (const float*)d_in[5];
    const float* Wo     = (const float*)d_in[6];
    const float* lq1    = (const float*)d_in[7];
    const float* lq2    = (const float*)d_in[8];
    const float* lk1    = (const float*)d_in[9];
    const float* lk2    = (const float*)d_in[10];
    const float* gamma  = (const float*)d_in[11];
    const float* beta   = (const float*)d_in[12];
    float* out = (float*)d_out;

    char* ws = (char*)d_ws;
    float* lam_ws   = (float*)ws;
    float* sum_ws   = (float*)(ws + 256);
    float* sumsq_ws = (float*)(ws + 512);
    float* colt_g   = (float*)(ws + 1024);          // 65536 floats = 256 KB
    unsigned short* Wob   = (unsigned short*)(ws + 1024 + 262144);
    unsigned short* QKVb  = Wob + 1048576;          // 4096 x 5120
    unsigned short* Xb    = QKVb + 20971520;        // 4096 x 1024
    unsigned short* Wqkvb = Xb + 4194304;           // 5120 x 1024
    unsigned short* VTb   = Wqkvb + 5242880;        // 32 x 64 x 2048
    unsigned short* attnb = Xb;                     // alias (X dead after QKV GEMM)
    unsigned short* normb = QKVb;                   // alias (QKV dead after attention)

    cvt5_kernel<<<10240, 256, 0, stream>>>(inputs, Wq, Wk, Wv, Wo, Xb, Wqkvb, Wob);
    lamcolt_kernel<<<64, 256, 0, stream>>>(lq1, lk1, lq2, lk2, tok, amask,
                                           lam_ws, sum_ws, sumsq_ws, colt_g);
    gemm_bt<true><<<dim3(40, 32), 256, 0, stream>>>(Xb, Wqkvb, QKVb, 4096, 5120, 1024);
    vt_kernel<<<dim3(32, 32), 256, 0, stream>>>(QKVb, VTb);
    attn_kernel<<<dim3(16, 32), 256, 0, stream>>>(QKVb, VTb, tok, colt_g, lam_ws,
                                                  attnb, sum_ws, sumsq_ws);
    norm_kernel<<<2048, 256, 0, stream>>>(attnb, sum_ws, sumsq_ws, gamma, beta, normb);
    gemm_bt<false><<<dim3(8, 32), 256, 0, stream>>>(normb, Wob, out, 4096, 1024, 1024);
}